// Round 1
// baseline (488.718 us; speedup 1.0000x reference)
//
#include <hip/hip_runtime.h>

using half8 = __attribute__((ext_vector_type(8))) _Float16;
using f32x4 = __attribute__((ext_vector_type(4))) float;

__device__ __forceinline__ float sigmf(float x) {
    return __builtin_amdgcn_rcpf(1.0f + __expf(-x));
}
__device__ __forceinline__ float tanhx(float x) {
    return 2.0f * __builtin_amdgcn_rcpf(1.0f + __expf(-2.0f * x)) - 1.0f;
}

// ---------------------------------------------------------------------------
// Prep: convert x + 12 weights to fp16 (pad odd K rows to even), sum biases.
// ---------------------------------------------------------------------------
struct PrepPtrs {
    const float* w[12];
    const float* bi[6];
    const float* bh[6];
    const float* x;
    _Float16* wdst[12];
    float* bdst;
    _Float16* xdst;
};

__global__ __launch_bounds__(256) void prep_kernel(PrepPtrs p) {
    int i = blockIdx.x * 256 + threadIdx.x;
    // segment 0: x [100*75][75] -> x16 [7500][76] (col 75 zero)
    if (i < 570000) {
        int row = i / 76, k = i - row * 76;
        float v = (k < 75) ? p.x[row * 75 + k] : 0.0f;
        p.xdst[i] = (_Float16)v;
        return;
    }
    i -= 570000;
    constexpr int wcnt[12] = {38912, 65536, 65536, 65536, 32768, 16384,
                              16384, 16384, 8192, 4096, 4096, 4096};
    #pragma unroll
    for (int j = 0; j < 12; ++j) {
        if (i < wcnt[j]) {
            float v;
            if (j == 0) {  // w_ih_1_0: [512][75] -> [512][76]
                int row = i / 76, k = i - row * 76;
                v = (k < 75) ? p.w[0][row * 75 + k] : 0.0f;
            } else {
                v = p.w[j][i];
            }
            p.wdst[j][i] = (_Float16)v;
            return;
        }
        i -= wcnt[j];
    }
    constexpr int bcnt[6] = {512, 512, 256, 256, 128, 128};
    constexpr int boff[6] = {0, 512, 1024, 1280, 1536, 1664};
    #pragma unroll
    for (int j = 0; j < 6; ++j) {
        if (i < bcnt[j]) {
            p.bdst[boff[j] + i] = p.bi[j][i] + p.bh[j][i];
            return;
        }
        i -= bcnt[j];
    }
}

// ---------------------------------------------------------------------------
// xg GEMM: C[7500][N] = A[7500][K] @ W[N][K]^T + bias[N]   (fp16 MFMA, f32 out)
// A row stride == W row stride == Kv (even, >= K, pad elems are zero).
// ---------------------------------------------------------------------------
template <int Ks>
__global__ __launch_bounds__(256) void gemm_xg(
    const _Float16* __restrict__ A, const _Float16* __restrict__ W,
    const float* __restrict__ bias, float* __restrict__ C, int Kv, int N) {
    constexpr int KP = Ks * 32;
    constexpr int LDK = KP + 8;
    __shared__ __align__(16) _Float16 Al[64][LDK];
    __shared__ __align__(16) _Float16 Wl[64][LDK];

    const int tid = threadIdx.x;
    const int m0 = blockIdx.x * 64;
    const int n0 = blockIdx.y * 64;
    constexpr int HP = KP / 2;  // dwords per LDS row (data region)

    for (int idx = tid; idx < 64 * HP; idx += 256) {
        int row = idx / HP;
        int k = (idx - row * HP) * 2;
        unsigned int va = 0, vw = 0;
        if (k < Kv) {
            int rg = m0 + row;
            if (rg > 7499) rg = 7499;
            va = *(const unsigned int*)(A + (size_t)rg * Kv + k);
            vw = *(const unsigned int*)(W + (size_t)(n0 + row) * Kv + k);
        }
        *(unsigned int*)&Al[row][k] = va;
        *(unsigned int*)&Wl[row][k] = vw;
    }
    __syncthreads();

    const int w = tid >> 6, l = tid & 63, hi = l >> 4;
    half8 a[Ks];
    #pragma unroll
    for (int kk = 0; kk < Ks; ++kk)
        a[kk] = *(const half8*)&Al[w * 16 + (l & 15)][kk * 32 + hi * 8];

    f32x4 acc[4];
    #pragma unroll
    for (int jt = 0; jt < 4; ++jt) {
        acc[jt] = f32x4{0.f, 0.f, 0.f, 0.f};
        #pragma unroll
        for (int kk = 0; kk < Ks; ++kk) {
            half8 b = *(const half8*)&Wl[jt * 16 + (l & 15)][kk * 32 + hi * 8];
            acc[jt] = __builtin_amdgcn_mfma_f32_16x16x32_f16(a[kk], b, acc[jt], 0, 0, 0);
        }
    }

    #pragma unroll
    for (int jt = 0; jt < 4; ++jt) {
        int n = n0 + jt * 16 + (l & 15);
        float bs = bias[n];
        #pragma unroll
        for (int r = 0; r < 4; ++r) {
            int m = m0 + w * 16 + hi * 4 + r;
            if (m < 7500) C[(size_t)m * N + n] = acc[jt][r] + bs;
        }
    }
}

// ---------------------------------------------------------------------------
// Recurrent layer: 7 blocks x 16 batch rows; w_hh fragments in registers;
// h double-buffered in LDS; xg prefetched one step ahead.
// gates laid out [i|f|g|o] * H; wave w owns hidden cols [w*16, w*16+16).
// ---------------------------------------------------------------------------
template <int H>
__global__ __launch_bounds__((H / 16) * 64) void lstm_rec(
    const float* __restrict__ xg,       // [7500][4H], bias already included
    const _Float16* __restrict__ whh,   // [4H][H] fp16
    _Float16* __restrict__ hout) {      // [100][75][H] fp16
    constexpr int Ks = H / 32;
    constexpr int NW = H / 16;
    constexpr int LDH = H + 8;
    constexpr int N4 = 4 * H;
    __shared__ __align__(16) _Float16 hbuf[2][16][LDH];

    const int tid = threadIdx.x;
    const int w = tid >> 6;
    const int l = tid & 63;
    const int hi = l >> 4;
    const int col = w * 16 + (l & 15);
    const int r0 = hi * 4;
    const int rb = blockIdx.x * 16;

    // Preload w_hh B-fragments (constant across all 75 steps).
    half8 bw[4][Ks];
    #pragma unroll
    for (int G = 0; G < 4; ++G)
        #pragma unroll
        for (int kk = 0; kk < Ks; ++kk)
            bw[G][kk] = *(const half8*)(whh + (size_t)(G * H + col) * H + kk * 32 + hi * 8);

    for (int i = tid; i < 2 * 16 * LDH; i += NW * 64)
        ((_Float16*)hbuf)[i] = (_Float16)0.0f;
    __syncthreads();

    // xg row base pointers for this lane's 4 batch rows (clamped).
    const float* xp[4];
    #pragma unroll
    for (int r = 0; r < 4; ++r) {
        int b = rb + r0 + r;
        if (b > 99) b = 99;
        xp[r] = xg + (size_t)b * 75 * N4 + col;
    }

    float xgn[16];
    #pragma unroll
    for (int G = 0; G < 4; ++G)
        #pragma unroll
        for (int r = 0; r < 4; ++r)
            xgn[G * 4 + r] = xp[r][G * H];  // t = 0

    f32x4 cst = {0.f, 0.f, 0.f, 0.f};

    for (int t = 0; t < 75; ++t) {
        float xgc[16];
        #pragma unroll
        for (int i = 0; i < 16; ++i) xgc[i] = xgn[i];
        const int tn = (t + 1 < 75) ? t + 1 : 74;
        #pragma unroll
        for (int G = 0; G < 4; ++G)
            #pragma unroll
            for (int r = 0; r < 4; ++r)
                xgn[G * 4 + r] = xp[r][(size_t)tn * N4 + G * H];

        const int cur = t & 1;
        half8 a[Ks];
        #pragma unroll
        for (int kk = 0; kk < Ks; ++kk)
            a[kk] = *(const half8*)&hbuf[cur][l & 15][kk * 32 + hi * 8];

        f32x4 acc[4];
        #pragma unroll
        for (int G = 0; G < 4; ++G) {
            acc[G] = f32x4{0.f, 0.f, 0.f, 0.f};
            #pragma unroll
            for (int kk = 0; kk < Ks; ++kk)
                acc[G] = __builtin_amdgcn_mfma_f32_16x16x32_f16(a[kk], bw[G][kk], acc[G], 0, 0, 0);
        }

        #pragma unroll
        for (int r = 0; r < 4; ++r) {
            float gi = acc[0][r] + xgc[0 + r];
            float gf = acc[1][r] + xgc[4 + r];
            float gg = acc[2][r] + xgc[8 + r];
            float go = acc[3][r] + xgc[12 + r];
            float si = sigmf(gi), sf = sigmf(gf), tg = tanhx(gg), so = sigmf(go);
            float cn = sf * cst[r] + si * tg;
            cst[r] = cn;
            float hn = so * tanhx(cn);
            _Float16 hv = (_Float16)hn;
            hbuf[cur ^ 1][r0 + r][col] = hv;
            int b = rb + r0 + r;
            if (b < 100) hout[((size_t)b * 75 + t) * H + col] = hv;
        }
        __syncthreads();
    }
}

// ---------------------------------------------------------------------------
// Final linear: out[100][60] = h[100][2400] @ lin_w[60][2400]^T + lin_b
// one wave per output element.
// ---------------------------------------------------------------------------
__global__ __launch_bounds__(256) void linear_out(
    const _Float16* __restrict__ h, const float* __restrict__ lw,
    const float* __restrict__ lb, float* __restrict__ out) {
    int wave = (blockIdx.x * blockDim.x + threadIdx.x) >> 6;
    int l = threadIdx.x & 63;
    if (wave >= 6000) return;
    int b = wave / 60, o = wave - b * 60;
    const _Float16* hp = h + (size_t)b * 2400;
    const float* wp = lw + (size_t)o * 2400;
    float acc = 0.f;
    for (int k = l; k < 2400; k += 64) acc += (float)hp[k] * wp[k];
    #pragma unroll
    for (int s = 32; s; s >>= 1) acc += __shfl_xor(acc, s, 64);
    if (l == 0) out[b * 60 + o] = acc + lb[o];
}

// ---------------------------------------------------------------------------
extern "C" void kernel_launch(void* const* d_in, const int* in_sizes, int n_in,
                              void* d_out, int out_size, void* d_ws, size_t ws_size,
                              hipStream_t stream) {
    const float* x = (const float*)d_in[0];
    const float* wih[6];
    const float* whhp[6];
    const float* bih[6];
    const float* bhh[6];
    for (int i = 0; i < 6; ++i) {
        wih[i] = (const float*)d_in[1 + 4 * i];
        whhp[i] = (const float*)d_in[2 + 4 * i];
        bih[i] = (const float*)d_in[3 + 4 * i];
        bhh[i] = (const float*)d_in[4 + 4 * i];
    }
    const float* lw = (const float*)d_in[25];
    const float* lb = (const float*)d_in[26];
    float* out = (float*)d_out;

    char* ws = (char*)d_ws;
    size_t cur = 0;
    auto alloc = [&](size_t b) {
        size_t o = cur;
        cur += (b + 255) & ~(size_t)255;
        return o;
    };
    _Float16* x16 = (_Float16*)(ws + alloc(7500 * 76 * 2));
    _Float16* w16[12];
    const size_t wbytes[12] = {77824, 131072, 131072, 131072, 65536, 32768,
                               32768, 32768, 16384, 8192, 8192, 8192};
    for (int i = 0; i < 12; ++i) w16[i] = (_Float16*)(ws + alloc(wbytes[i]));
    float* biasp = (float*)(ws + alloc(7168));
    float* xg = (float*)(ws + alloc((size_t)7500 * 512 * 4));
    _Float16* hA = (_Float16*)(ws + alloc((size_t)100 * 75 * 128 * 2));
    _Float16* hB = (_Float16*)(ws + alloc((size_t)100 * 75 * 128 * 2));

    PrepPtrs pp;
    for (int i = 0; i < 6; ++i) {
        pp.w[2 * i] = wih[i];
        pp.w[2 * i + 1] = whhp[i];
        pp.bi[i] = bih[i];
        pp.bh[i] = bhh[i];
        pp.wdst[2 * i] = w16[2 * i];
        pp.wdst[2 * i + 1] = w16[2 * i + 1];
    }
    pp.x = x;
    pp.xdst = x16;
    pp.bdst = biasp;
    prep_kernel<<<3554, 256, 0, stream>>>(pp);

    // layer 0: I=75 (Kv=76), H=128
    gemm_xg<3><<<dim3(118, 8), 256, 0, stream>>>(x16, w16[0], biasp + 0, xg, 76, 512);
    lstm_rec<128><<<7, 512, 0, stream>>>(xg, w16[1], hA);
    // layer 1: I=128, H=128
    gemm_xg<4><<<dim3(118, 8), 256, 0, stream>>>(hA, w16[2], biasp + 512, xg, 128, 512);
    lstm_rec<128><<<7, 512, 0, stream>>>(xg, w16[3], hB);
    // layer 2: I=128, H=64
    gemm_xg<4><<<dim3(118, 4), 256, 0, stream>>>(hB, w16[4], biasp + 1024, xg, 128, 256);
    lstm_rec<64><<<7, 256, 0, stream>>>(xg, w16[5], hA);
    // layer 3: I=64, H=64
    gemm_xg<2><<<dim3(118, 4), 256, 0, stream>>>(hA, w16[6], biasp + 1280, xg, 64, 256);
    lstm_rec<64><<<7, 256, 0, stream>>>(xg, w16[7], hB);
    // layer 4: I=64, H=32
    gemm_xg<2><<<dim3(118, 2), 256, 0, stream>>>(hB, w16[8], biasp + 1536, xg, 64, 128);
    lstm_rec<32><<<7, 128, 0, stream>>>(xg, w16[9], hA);
    // layer 5: I=32, H=32
    gemm_xg<1><<<dim3(118, 2), 256, 0, stream>>>(hA, w16[10], biasp + 1664, xg, 32, 128);
    lstm_rec<32><<<7, 128, 0, stream>>>(xg, w16[11], hB);

    linear_out<<<1500, 256, 0, stream>>>(hB, lw, lb, out);
}

// Round 2
// 374.747 us; speedup vs baseline: 1.3041x; 1.3041x over previous
//
#include <hip/hip_runtime.h>

using half8 = __attribute__((ext_vector_type(8))) _Float16;
using f32x4 = __attribute__((ext_vector_type(4))) float;

__device__ __forceinline__ float sigmf(float x) {
    return __builtin_amdgcn_rcpf(1.0f + __expf(-x));
}
__device__ __forceinline__ float tanhx(float x) {
    return 2.0f * __builtin_amdgcn_rcpf(1.0f + __expf(-2.0f * x)) - 1.0f;
}

// ---------------------------------------------------------------------------
// Prep: fp32->fp16 conversions + layout transforms (one-time, parallel):
//  x16   : [75][112][76] fp16  (transposed from x[100][75][75], zero-padded)
//  wihI  : per layer [4H][Kv] fp16, ROW-INTERLEAVED: row n holds original
//          gate row (n&3)*H + (n>>2)  -> GEMM output columns come out as
//          [col*4 + gate], i.e. i,f,g,o adjacent per hidden column.
//  whh16 : per layer [4H][H] fp16 (plain convert, original gate order)
//  biasI : summed b_ih+b_hh, interleaved to match wihI columns.
// ---------------------------------------------------------------------------
struct PrepPtrs {
    const float* wih[6];
    const float* whh[6];
    const float* bi[6];
    const float* bh[6];
    const float* x;
    _Float16* wihI[6];
    _Float16* whh16[6];
    float* biasI;
    _Float16* x16;
};

__global__ __launch_bounds__(256) void prep_kernel(PrepPtrs p) {
    int i = blockIdx.x * 256 + threadIdx.x;
    // x16: 8448 rows x 76
    if (i < 642048) {
        int row = i / 76, k = i - row * 76;
        int t = row / 112, b = row - t * 112;
        float v = (b < 100 && k < 75 && t < 75)
                      ? p.x[((size_t)b * 75 + t) * 75 + k]
                      : 0.0f;
        p.x16[i] = (_Float16)v;
        return;
    }
    i -= 642048;
    constexpr int HH[6] = {128, 128, 64, 64, 32, 32};
    constexpr int KK[6] = {75, 128, 128, 64, 64, 32};
    constexpr int KV[6] = {76, 128, 128, 64, 64, 32};
    #pragma unroll
    for (int lyr = 0; lyr < 6; ++lyr) {
        int cnt = 4 * HH[lyr] * KV[lyr];
        if (i < cnt) {
            int n = i / KV[lyr], k = i - n * KV[lyr];
            int col = n >> 2, G = n & 3;
            float v = (k < KK[lyr])
                          ? p.wih[lyr][(size_t)(G * HH[lyr] + col) * KK[lyr] + k]
                          : 0.0f;
            p.wihI[lyr][i] = (_Float16)v;
            return;
        }
        i -= cnt;
    }
    #pragma unroll
    for (int lyr = 0; lyr < 6; ++lyr) {
        int cnt = 4 * HH[lyr] * HH[lyr];
        if (i < cnt) {
            p.whh16[lyr][i] = (_Float16)p.whh[lyr][i];
            return;
        }
        i -= cnt;
    }
    constexpr int BOFF[6] = {0, 512, 1024, 1280, 1536, 1664};
    #pragma unroll
    for (int lyr = 0; lyr < 6; ++lyr) {
        int cnt = 4 * HH[lyr];
        if (i < cnt) {
            int col = i >> 2, G = i & 3;
            int src = G * HH[lyr] + col;
            p.biasI[BOFF[lyr] + i] = p.bi[lyr][src] + p.bh[lyr][src];
            return;
        }
        i -= cnt;
    }
}

// ---------------------------------------------------------------------------
// xg GEMM: C[8448][N] = A[8448][Kv] @ W[N][Kv]^T + bias[N]  (fp16 MFMA, f32)
// Rows are [t][b] flattened (112-padded batch). No bounds checks: all
// buffers are padded to 8448+ rows; pad rows hold bounded garbage.
// ---------------------------------------------------------------------------
template <int Ks>
__global__ __launch_bounds__(256) void gemm_xg(
    const _Float16* __restrict__ A, const _Float16* __restrict__ W,
    const float* __restrict__ bias, float* __restrict__ C, int Kv, int N) {
    constexpr int KP = Ks * 32;
    constexpr int LDK = KP + 8;
    __shared__ __align__(16) _Float16 Al[64][LDK];
    __shared__ __align__(16) _Float16 Wl[64][LDK];

    const int tid = threadIdx.x;
    const int m0 = blockIdx.x * 64;
    const int n0 = blockIdx.y * 64;
    constexpr int HP = KP / 2;

    for (int idx = tid; idx < 64 * HP; idx += 256) {
        int row = idx / HP;
        int k = (idx - row * HP) * 2;
        unsigned int va = 0, vw = 0;
        if (k < Kv) {
            va = *(const unsigned int*)(A + (size_t)(m0 + row) * Kv + k);
            vw = *(const unsigned int*)(W + (size_t)(n0 + row) * Kv + k);
        }
        *(unsigned int*)&Al[row][k] = va;
        *(unsigned int*)&Wl[row][k] = vw;
    }
    __syncthreads();

    const int w = tid >> 6, l = tid & 63, hi = l >> 4;
    half8 a[Ks];
    #pragma unroll
    for (int kk = 0; kk < Ks; ++kk)
        a[kk] = *(const half8*)&Al[w * 16 + (l & 15)][kk * 32 + hi * 8];

    f32x4 acc[4];
    #pragma unroll
    for (int jt = 0; jt < 4; ++jt) {
        acc[jt] = f32x4{0.f, 0.f, 0.f, 0.f};
        #pragma unroll
        for (int kk = 0; kk < Ks; ++kk) {
            half8 b = *(const half8*)&Wl[jt * 16 + (l & 15)][kk * 32 + hi * 8];
            acc[jt] = __builtin_amdgcn_mfma_f32_16x16x32_f16(a[kk], b, acc[jt], 0, 0, 0);
        }
    }

    #pragma unroll
    for (int jt = 0; jt < 4; ++jt) {
        int n = n0 + jt * 16 + (l & 15);
        float bs = bias[n];
        #pragma unroll
        for (int r = 0; r < 4; ++r) {
            int m = m0 + w * 16 + hi * 4 + r;
            C[(size_t)m * N + n] = acc[jt][r] + bs;
        }
    }
}

// ---------------------------------------------------------------------------
// Recurrent layer. 7 blocks x 16 batch rows; w_hh fragments in registers;
// h double-buffered in LDS; xg prefetched 2 steps ahead as dwordx4
// (gate-interleaved layout). RAW s_barrier + lgkmcnt(0) only -- global
// loads/stores stay in flight across the barrier (counted vmcnt at use).
// ---------------------------------------------------------------------------
template <int H>
__global__ __launch_bounds__((H / 16) * 64) void lstm_rec(
    const float* __restrict__ xg,       // [75+2][112][H][4] f32 (i,f,g,o)
    const _Float16* __restrict__ whh,   // [4H][H] fp16
    _Float16* __restrict__ hout) {      // [75][112][H] fp16
    constexpr int Ks = H / 32;
    constexpr int NW = H / 16;
    constexpr int LDH = H + 8;
    constexpr int XSTR = 112 * 4 * H;   // floats per timestep in xg
    constexpr int HSTR = 112 * H;       // halfs per timestep in hout

    __shared__ __align__(16) _Float16 hbuf[2][16][LDH];

    const int tid = threadIdx.x;
    const int w = tid >> 6, l = tid & 63, hi = l >> 4;
    const int col = w * 16 + (l & 15);
    const int brow = blockIdx.x * 16 + hi * 4;

    half8 bw[4][Ks];
    #pragma unroll
    for (int G = 0; G < 4; ++G)
        #pragma unroll
        for (int kk = 0; kk < Ks; ++kk)
            bw[G][kk] = *(const half8*)(whh + (size_t)(G * H + col) * H + kk * 32 + hi * 8);

    for (int i = tid; i < 2 * 16 * LDH; i += NW * 64) ((_Float16*)hbuf)[i] = (_Float16)0;
    __syncthreads();

    const float* xp0 = xg + (size_t)(brow + 0) * (4 * H) + col * 4;
    const float* xp1 = xg + (size_t)(brow + 1) * (4 * H) + col * 4;
    const float* xp2 = xg + (size_t)(brow + 2) * (4 * H) + col * 4;
    const float* xp3 = xg + (size_t)(brow + 3) * (4 * H) + col * 4;
    _Float16* hop = hout + (size_t)brow * H + col;

    f32x4 P0[4], P1[4];
    P0[0] = *(const f32x4*)xp0;
    P0[1] = *(const f32x4*)xp1;
    P0[2] = *(const f32x4*)xp2;
    P0[3] = *(const f32x4*)xp3;
    P1[0] = *(const f32x4*)(xp0 + XSTR);
    P1[1] = *(const f32x4*)(xp1 + XSTR);
    P1[2] = *(const f32x4*)(xp2 + XSTR);
    P1[3] = *(const f32x4*)(xp3 + XSTR);
    xp0 += 2 * XSTR; xp1 += 2 * XSTR; xp2 += 2 * XSTR; xp3 += 2 * XSTR;

    float cst[4] = {0.f, 0.f, 0.f, 0.f};

#define LSTM_STEP(P, CUR)                                                     \
    {                                                                         \
        half8 a[Ks];                                                          \
        _Pragma("unroll") for (int kk = 0; kk < Ks; ++kk)                     \
            a[kk] = *(const half8*)&hbuf[CUR][l & 15][kk * 32 + hi * 8];      \
        f32x4 acc[4];                                                         \
        _Pragma("unroll") for (int G = 0; G < 4; ++G) {                       \
            acc[G] = f32x4{0.f, 0.f, 0.f, 0.f};                               \
            _Pragma("unroll") for (int kk = 0; kk < Ks; ++kk)                 \
                acc[G] = __builtin_amdgcn_mfma_f32_16x16x32_f16(              \
                    a[kk], bw[G][kk], acc[G], 0, 0, 0);                       \
        }                                                                     \
        float gi[4], gf[4], gg[4], go[4];                                     \
        _Pragma("unroll") for (int r = 0; r < 4; ++r) {                       \
            gi[r] = acc[0][r] + P[r][0];                                      \
            gf[r] = acc[1][r] + P[r][1];                                      \
            gg[r] = acc[2][r] + P[r][2];                                      \
            go[r] = acc[3][r] + P[r][3];                                      \
        }                                                                     \
        P[0] = *(const f32x4*)xp0;                                            \
        P[1] = *(const f32x4*)xp1;                                            \
        P[2] = *(const f32x4*)xp2;                                            \
        P[3] = *(const f32x4*)xp3;                                            \
        xp0 += XSTR; xp1 += XSTR; xp2 += XSTR; xp3 += XSTR;                   \
        _Pragma("unroll") for (int r = 0; r < 4; ++r) {                       \
            float cn = sigmf(gf[r]) * cst[r] + sigmf(gi[r]) * tanhx(gg[r]);   \
            cst[r] = cn;                                                      \
            float hn = sigmf(go[r]) * tanhx(cn);                              \
            _Float16 hv = (_Float16)hn;                                       \
            hbuf[CUR ^ 1][hi * 4 + r][col] = hv;                              \
            hop[r * H] = hv;                                                  \
        }                                                                     \
        hop += HSTR;                                                          \
        asm volatile("s_waitcnt lgkmcnt(0)" ::: "memory");                    \
        __builtin_amdgcn_s_barrier();                                         \
        asm volatile("" ::: "memory");                                        \
    }

    #pragma unroll 1
    for (int it = 0; it < 37; ++it) {
        LSTM_STEP(P0, 0)
        LSTM_STEP(P1, 1)
    }
    LSTM_STEP(P0, 0)
#undef LSTM_STEP
}

// ---------------------------------------------------------------------------
// Final linear: out[100][60] = h[.][2400] @ lin_w[60][2400]^T + lin_b,
// h stored as [75][112][32] fp16 (k = t*32 + hc). One wave per (b,o).
// ---------------------------------------------------------------------------
__global__ __launch_bounds__(256) void linear_out(
    const _Float16* __restrict__ h, const float* __restrict__ lw,
    const float* __restrict__ lb, float* __restrict__ out) {
    int wave = (blockIdx.x * 256 + threadIdx.x) >> 6;
    int l = threadIdx.x & 63;
    if (wave >= 6000) return;
    int b = wave / 60, o = wave - b * 60;
    int hc = l & 31, t0 = l >> 5;
    float acc = 0.f;
    for (int t = t0; t < 75; t += 2)
        acc += (float)h[((size_t)t * 112 + b) * 32 + hc] * lw[(size_t)o * 2400 + t * 32 + hc];
    #pragma unroll
    for (int s = 32; s; s >>= 1) acc += __shfl_xor(acc, s, 64);
    if (l == 0) out[b * 60 + o] = acc + lb[o];
}

// ---------------------------------------------------------------------------
extern "C" void kernel_launch(void* const* d_in, const int* in_sizes, int n_in,
                              void* d_out, int out_size, void* d_ws, size_t ws_size,
                              hipStream_t stream) {
    const float* x = (const float*)d_in[0];
    const float* wih[6];
    const float* whhp[6];
    const float* bih[6];
    const float* bhh[6];
    for (int i = 0; i < 6; ++i) {
        wih[i] = (const float*)d_in[1 + 4 * i];
        whhp[i] = (const float*)d_in[2 + 4 * i];
        bih[i] = (const float*)d_in[3 + 4 * i];
        bhh[i] = (const float*)d_in[4 + 4 * i];
    }
    const float* lw = (const float*)d_in[25];
    const float* lb = (const float*)d_in[26];
    float* out = (float*)d_out;

    char* ws = (char*)d_ws;
    size_t cur = 0;
    auto alloc = [&](size_t b) {
        size_t o = cur;
        cur += (b + 255) & ~(size_t)255;
        return o;
    };
    _Float16* x16 = (_Float16*)(ws + alloc((size_t)8448 * 76 * 2));
    _Float16* wI[6];
    const size_t wihBytes[6] = {77824, 131072, 65536, 32768, 16384, 8192};
    for (int i = 0; i < 6; ++i) wI[i] = (_Float16*)(ws + alloc(wihBytes[i]));
    _Float16* wH[6];
    const size_t whhBytes[6] = {131072, 131072, 32768, 32768, 8192, 8192};
    for (int i = 0; i < 6; ++i) wH[i] = (_Float16*)(ws + alloc(whhBytes[i]));
    float* biasI = (float*)(ws + alloc(1792 * 4));
    float* xg = (float*)(ws + alloc((size_t)8672 * 512 * 4));  // +2t slack
    _Float16* hA = (_Float16*)(ws + alloc((size_t)8448 * 128 * 2));
    _Float16* hB = (_Float16*)(ws + alloc((size_t)8448 * 128 * 2));

    PrepPtrs pp;
    for (int i = 0; i < 6; ++i) {
        pp.wih[i] = wih[i];
        pp.whh[i] = whhp[i];
        pp.bi[i] = bih[i];
        pp.bh[i] = bhh[i];
        pp.wihI[i] = wI[i];
        pp.whh16[i] = wH[i];
    }
    pp.x = x;
    pp.biasI = biasI;
    pp.x16 = x16;
    prep_kernel<<<3835, 256, 0, stream>>>(pp);

    // layer 0: I=75 (Kv=76), H=128
    gemm_xg<3><<<dim3(132, 8), 256, 0, stream>>>(x16, wI[0], biasI + 0, xg, 76, 512);
    lstm_rec<128><<<7, 512, 0, stream>>>(xg, wH[0], hA);
    // layer 1: I=128, H=128
    gemm_xg<4><<<dim3(132, 8), 256, 0, stream>>>(hA, wI[1], biasI + 512, xg, 128, 512);
    lstm_rec<128><<<7, 512, 0, stream>>>(xg, wH[1], hB);
    // layer 2: I=128, H=64
    gemm_xg<4><<<dim3(132, 4), 256, 0, stream>>>(hB, wI[2], biasI + 1024, xg, 128, 256);
    lstm_rec<64><<<7, 256, 0, stream>>>(xg, wH[2], hA);
    // layer 3: I=64, H=64
    gemm_xg<2><<<dim3(132, 4), 256, 0, stream>>>(hA, wI[3], biasI + 1280, xg, 64, 256);
    lstm_rec<64><<<7, 256, 0, stream>>>(xg, wH[3], hB);
    // layer 4: I=64, H=32
    gemm_xg<2><<<dim3(132, 2), 256, 0, stream>>>(hB, wI[4], biasI + 1536, xg, 64, 128);
    lstm_rec<32><<<7, 128, 0, stream>>>(xg, wH[4], hA);
    // layer 5: I=32, H=32
    gemm_xg<1><<<dim3(132, 2), 256, 0, stream>>>(hA, wI[5], biasI + 1664, xg, 32, 128);
    lstm_rec<32><<<7, 128, 0, stream>>>(xg, wH[5], hB);

    linear_out<<<1500, 256, 0, stream>>>(hB, lw, lb, out);
}